// Round 18
// baseline (249.100 us; speedup 1.0000x reference)
//
#include <hip/hip_runtime.h>
#include <hip/hip_bf16.h>
#include <cstdint>

typedef __bf16 v8bf __attribute__((ext_vector_type(8)));
typedef float  v4f  __attribute__((ext_vector_type(4)));

__device__ __forceinline__ unsigned short b16(float f) {
  union { float f; unsigned u; } v; v.f = f;
  unsigned u = v.u;
  return (unsigned short)((u + 0x7fffu + ((u >> 16) & 1u)) >> 16);
}
__device__ __forceinline__ float bf2f(unsigned short u) {
  union { unsigned u; float f; } v; v.u = ((unsigned)u) << 16; return v.f;
}
// raw 2^x — v_exp_f32 IS exp2; bypasses libm exp2f's precise path (R11 lesson)
__device__ __forceinline__ float exp2_raw(float x) {
  float r;
  asm("v_exp_f32 %0, %1" : "=v"(r) : "v"(x));
  return r;
}

#define GLOAD_LDS16(g, l)                                                     \
  __builtin_amdgcn_global_load_lds(                                           \
      (const __attribute__((address_space(1))) void*)(g),                     \
      (__attribute__((address_space(3))) void*)(l), 16, 0, 0)

// ---------------- prep: x fp32->bf16 convert + all 9 weight transposes, ONE launch --------
__global__ __launch_bounds__(256) void prep(const float* __restrict__ x,
                                            unsigned short* __restrict__ xb,
                                            const float* __restrict__ Wdq,
                                            const float* __restrict__ Wdkv,
                                            const float* __restrict__ Wkr,
                                            const float* __restrict__ Wuq,
                                            const float* __restrict__ Wqr,
                                            const float* __restrict__ Wuk,
                                            const float* __restrict__ Wuv,
                                            const float* __restrict__ Wout,
                                            unsigned short* __restrict__ W1T,
                                            unsigned short* __restrict__ W2T,
                                            unsigned short* __restrict__ W3T,
                                            unsigned short* __restrict__ WoT) {
  const int tid = threadIdx.x;
  int bid = blockIdx.x;
  if (bid < 8192) {
    size_t idx = (size_t)bid * 256 + tid;
    v4f v = *(const v4f*)(x + idx * 4);
    unsigned long long p = (unsigned long long)b16(v[0]) |
                           ((unsigned long long)b16(v[1]) << 16) |
                           ((unsigned long long)b16(v[2]) << 32) |
                           ((unsigned long long)b16(v[3]) << 48);
    *(unsigned long long*)(xb + idx * 4) = p;
    return;
  }
  __shared__ float tile[32][33];
  bid -= 8192;
  const float* in; unsigned short* out; int C, R, gx;
  if (bid < 1024)      { in = Wdq;  out = W1T;                        C = 512;  R = 2048; gx = 16; }
  else if (bid < 2048) { in = Wdkv; out = W1T + (size_t)512 * 2048;   C = 512;  R = 2048; gx = 16; bid -= 1024; }
  else if (bid < 4096) { in = Wkr;  out = W1T + (size_t)1024 * 2048;  C = 1024; R = 2048; gx = 32; bid -= 2048; }
  else if (bid < 4608) { in = Wuq;  out = W2T;                        C = 1024; R = 512;  gx = 32; bid -= 4096; }
  else if (bid < 5120) { in = Wqr;  out = W2T + (size_t)1024 * 512;   C = 1024; R = 512;  gx = 32; bid -= 4608; }
  else if (bid < 5632) { in = Wuk;  out = W3T;                        C = 1024; R = 512;  gx = 32; bid -= 5120; }
  else if (bid < 6656) { in = Wuv;  out = W3T + (size_t)1024 * 512;   C = 2048; R = 512;  gx = 64; bid -= 5632; }
  else                 { in = Wout; out = WoT;                        C = 2048; R = 2048; gx = 64; bid -= 6656; }
  const int c0 = (bid % gx) * 32, r0 = (bid / gx) * 32;
  const int xx = tid & 31, yy = tid >> 5;
#pragma unroll
  for (int i = 0; i < 4; ++i)
    tile[yy + 8 * i][xx] = in[(size_t)(r0 + yy + 8 * i) * C + c0 + xx];
  __syncthreads();
#pragma unroll
  for (int i = 0; i < 4; ++i)
    out[(size_t)(c0 + yy + 8 * i) * R + r0 + xx] = b16(tile[xx][yy + 8 * i]);
}

// ---------------- GEMM: C[M,N] = A[M,K](bf16) * BT[N,K](bf16) ----------------
// m97 recipe: 128x128 tile, BK=32, 4 waves (2x2), global_load_lds width=16,
// LINEAR [128][32] LDS. Bijective XCD swizzle (nwg % 8 == 0).
// MODE 0: fp32 + bias -> C0.  MODE 1: bf16 -> C0 (stride N).
template <int MODE>
__global__ __launch_bounds__(256) void gemm_bt(const unsigned short* __restrict__ A,
                                               const unsigned short* __restrict__ BT,
                                               void* __restrict__ C0,
                                               const float* __restrict__ bias,
                                               int M, int N, int K) {
  __shared__ unsigned short As[128 * 32];
  __shared__ unsigned short Bs[128 * 32];
  const int tid = threadIdx.x;
  const int w = tid >> 6, l = tid & 63;
  const int wm = w >> 1, wn = w & 1;
  const int lg = l >> 4, lr = l & 15;
  const int nwg = gridDim.x * gridDim.y;
  const int f = blockIdx.y * gridDim.x + blockIdx.x;
  const int swz = (f & 7) * (nwg >> 3) + (f >> 3);
  const int m0 = (swz / gridDim.x) * 128, n0 = (swz % gridDim.x) * 128;

  const int srow = tid >> 2, scol = (tid & 3) * 8;
  const unsigned short* Ap0 = A  + (size_t)(m0 + srow) * K + scol;
  const unsigned short* Ap1 = A  + (size_t)(m0 + 64 + srow) * K + scol;
  const unsigned short* Bp0 = BT + (size_t)(n0 + srow) * K + scol;
  const unsigned short* Bp1 = BT + (size_t)(n0 + 64 + srow) * K + scol;
  unsigned short* Ad0 = As + tid * 8;
  unsigned short* Ad1 = As + 2048 + tid * 8;
  unsigned short* Bd0 = Bs + tid * 8;
  unsigned short* Bd1 = Bs + 2048 + tid * 8;

  v4f acc[4][4];
#pragma unroll
  for (int i = 0; i < 4; ++i)
#pragma unroll
    for (int j = 0; j < 4; ++j) acc[i][j] = (v4f){0.f, 0.f, 0.f, 0.f};

  for (int k0 = 0; k0 < K; k0 += 32) {
    GLOAD_LDS16(Ap0 + k0, Ad0);
    GLOAD_LDS16(Ap1 + k0, Ad1);
    GLOAD_LDS16(Bp0 + k0, Bd0);
    GLOAD_LDS16(Bp1 + k0, Bd1);
    __syncthreads();
    v8bf af[4], bfr[4];
#pragma unroll
    for (int mi = 0; mi < 4; ++mi)
      af[mi] = *(const v8bf*)&As[(wm * 64 + mi * 16 + lr) * 32 + lg * 8];
#pragma unroll
    for (int ni = 0; ni < 4; ++ni)
      bfr[ni] = *(const v8bf*)&Bs[(wn * 64 + ni * 16 + lr) * 32 + lg * 8];
#pragma unroll
    for (int mi = 0; mi < 4; ++mi)
#pragma unroll
      for (int ni = 0; ni < 4; ++ni)
        acc[mi][ni] = __builtin_amdgcn_mfma_f32_16x16x32_bf16(af[mi], bfr[ni], acc[mi][ni], 0, 0, 0);
    __syncthreads();
  }
#pragma unroll
  for (int mi = 0; mi < 4; ++mi)
#pragma unroll
    for (int ni = 0; ni < 4; ++ni) {
      const int col = n0 + wn * 64 + ni * 16 + lr;
#pragma unroll
      for (int rr = 0; rr < 4; ++rr) {
        const int row = m0 + wm * 64 + mi * 16 + lg * 4 + rr;
        const float v = acc[mi][ni][rr];
        if (MODE == 0) {
          ((float*)C0)[(size_t)row * N + col] = v + bias[col];
        } else {
          ((unsigned short*)C0)[(size_t)row * N + col] = b16(v);
        }
      }
    }
}

// ---------------- merged GEMM2+GEMM3 (both K=512, independent) ----------------
__global__ __launch_bounds__(256) void gemm23(const unsigned short* __restrict__ cq,
                                              const unsigned short* __restrict__ ckv,
                                              const unsigned short* __restrict__ W2T,
                                              const unsigned short* __restrict__ W3T,
                                              unsigned short* __restrict__ Qb,
                                              unsigned short* __restrict__ Kb,
                                              unsigned short* __restrict__ VT) {
  __shared__ unsigned short As[128 * 32];
  __shared__ unsigned short Bs[128 * 32];
  const int tid = threadIdx.x;
  const int w = tid >> 6, l = tid & 63;
  const int wm = w >> 1, wn = w & 1;
  const int lg = l >> 4, lr = l & 15;
  const int f = blockIdx.x;                      // 0..1279
  const int swz = (f & 7) * 160 + (f >> 3);      // bijective XCD swizzle (1280/8=160)
  const bool is3 = swz >= 512;
  const int t = is3 ? swz - 512 : swz;
  const int gx = is3 ? 24 : 16;
  const int m0 = (t / gx) * 128, n0 = (t % gx) * 128;
  const unsigned short* A  = is3 ? ckv : cq;
  const unsigned short* BT = is3 ? W3T : W2T;
  const int K = 512;

  const int srow = tid >> 2, scol = (tid & 3) * 8;
  const unsigned short* Ap0 = A  + (size_t)(m0 + srow) * K + scol;
  const unsigned short* Ap1 = A  + (size_t)(m0 + 64 + srow) * K + scol;
  const unsigned short* Bp0 = BT + (size_t)(n0 + srow) * K + scol;
  const unsigned short* Bp1 = BT + (size_t)(n0 + 64 + srow) * K + scol;
  unsigned short* Ad0 = As + tid * 8;
  unsigned short* Ad1 = As + 2048 + tid * 8;
  unsigned short* Bd0 = Bs + tid * 8;
  unsigned short* Bd1 = Bs + 2048 + tid * 8;

  v4f acc[4][4];
#pragma unroll
  for (int i = 0; i < 4; ++i)
#pragma unroll
    for (int j = 0; j < 4; ++j) acc[i][j] = (v4f){0.f, 0.f, 0.f, 0.f};

  for (int k0 = 0; k0 < K; k0 += 32) {
    GLOAD_LDS16(Ap0 + k0, Ad0);
    GLOAD_LDS16(Ap1 + k0, Ad1);
    GLOAD_LDS16(Bp0 + k0, Bd0);
    GLOAD_LDS16(Bp1 + k0, Bd1);
    __syncthreads();
    v8bf af[4], bfr[4];
#pragma unroll
    for (int mi = 0; mi < 4; ++mi)
      af[mi] = *(const v8bf*)&As[(wm * 64 + mi * 16 + lr) * 32 + lg * 8];
#pragma unroll
    for (int ni = 0; ni < 4; ++ni)
      bfr[ni] = *(const v8bf*)&Bs[(wn * 64 + ni * 16 + lr) * 32 + lg * 8];
#pragma unroll
    for (int mi = 0; mi < 4; ++mi)
#pragma unroll
      for (int ni = 0; ni < 4; ++ni)
        acc[mi][ni] = __builtin_amdgcn_mfma_f32_16x16x32_bf16(af[mi], bfr[ni], acc[mi][ni], 0, 0, 0);
    __syncthreads();
  }

#pragma unroll
  for (int mi = 0; mi < 4; ++mi)
#pragma unroll
    for (int ni = 0; ni < 4; ++ni) {
      const int col = n0 + wn * 64 + ni * 16 + lr;
      const int row0 = m0 + wm * 64 + mi * 16 + lg * 4;
      if (!is3) {
        if (col < 1024) {
          int qc = (col >> 6) * 128 + (col & 63);
#pragma unroll
          for (int rr = 0; rr < 4; ++rr)
            Qb[(size_t)(row0 + rr) * 2048 + qc] = b16(acc[mi][ni][rr]);
        } else {
          int cc = col - 1024, d = cc & 63;
          int qc = (cc >> 6) * 128 + 64 + d;
#pragma unroll
          for (int rr = 0; rr < 4; ++rr) {
            int s = (row0 + rr) & 2047;
            float ang = (float)s * __expf(-(float)(d & 31) * 0.14391156831f);
            float sn, cs; __sincosf(ang, &sn, &cs);
            Qb[(size_t)(row0 + rr) * 2048 + qc] = b16(acc[mi][ni][rr] * (cs + sn));
          }
        }
      } else {
        if (col < 1024) {
          int kc = (col >> 6) * 128 + (col & 63);
#pragma unroll
          for (int rr = 0; rr < 4; ++rr)
            Kb[(size_t)(row0 + rr) * 2048 + kc] = b16(acc[mi][ni][rr]);
        } else {
          int hd = col - 1024, h = hd >> 7, d = hd & 127;
          int b = row0 >> 11, s = row0 & 2047;
          unsigned long long p =
              (unsigned long long)b16(acc[mi][ni][0]) |
              ((unsigned long long)b16(acc[mi][ni][1]) << 16) |
              ((unsigned long long)b16(acc[mi][ni][2]) << 32) |
              ((unsigned long long)b16(acc[mi][ni][3]) << 48);
          *(unsigned long long*)&VT[(size_t)((b * 16 + h) * 128 + d) * 2048 + s] = p;
        }
      }
    }
}

// ---------------- RMSNorm + RoPE k_rot ----------------
__global__ __launch_bounds__(256) void rmsnorm_rope(const unsigned short* __restrict__ T1,
                                                    const float* __restrict__ gq,
                                                    const float* __restrict__ gkv,
                                                    unsigned short* __restrict__ cq,
                                                    unsigned short* __restrict__ ckv,
                                                    unsigned short* __restrict__ Kb) {
  const int row = blockIdx.x;
  const int t = threadIdx.x;
  const int s = row & 2047;
  const unsigned short* rp = T1 + (size_t)row * 2048;
  float xq0 = bf2f(rp[t]), xq1 = bf2f(rp[256 + t]);
  float xk0 = bf2f(rp[512 + t]), xk1 = bf2f(rp[768 + t]);
  float sq = xq0 * xq0 + xq1 * xq1;
  float sk = xk0 * xk0 + xk1 * xk1;
#pragma unroll
  for (int o = 1; o < 64; o <<= 1) { sq += __shfl_xor(sq, o); sk += __shfl_xor(sk, o); }
  __shared__ float red[8];
  if ((t & 63) == 0) { red[t >> 6] = sq; red[4 + (t >> 6)] = sk; }
  __syncthreads();
  float rq = rsqrtf((red[0] + red[1] + red[2] + red[3]) * (1.f / 512.f) + 1e-5f);
  float rk = rsqrtf((red[4] + red[5] + red[6] + red[7]) * (1.f / 512.f) + 1e-5f);
  cq[(size_t)row * 512 + t]        = b16(gq[t] * xq0 * rq);
  cq[(size_t)row * 512 + 256 + t]  = b16(gq[256 + t] * xq1 * rq);
  ckv[(size_t)row * 512 + t]       = b16(gkv[t] * xk0 * rk);
  ckv[(size_t)row * 512 + 256 + t] = b16(gkv[256 + t] * xk1 * rk);
#pragma unroll
  for (int i = 0; i < 4; ++i) {
    int j = t + 256 * i;                 // 0..1023
    int hh = j >> 6, d = j & 63;
    float ang = (float)s * __expf(-(float)(d & 31) * 0.14391156831f); // ln(10000)/64
    float sn, cs; __sincosf(ang, &sn, &cs);
    Kb[(size_t)row * 2048 + hh * 128 + 64 + d] = b16(bf2f(rp[1024 + j]) * (cs + sn));
  }
}

// ---------------- causal flash attention ----------------
// R18: R17 (8-wave KV-shared CTA, within-CTA complementary pairing, K/V LDS
// double-buffer) + Ps shrunk to stride-64 with XOR swizzle (byte^=(row&7)<<4
// on both the 2B writes and 16B reads; padding dropped). Total LDS exactly
// 80KB -> 2 CTAs/CU (16 waves/CU): cross-CTA overlap STACKED on dbuf.
// Balance is guaranteed: every CTA does exactly 34 tiles (2jj+2 + 2(15-jj)+2).
// Fixed-ref exp2 softmax (R13), raw v_exp_f32 (R11), T5 setprio.
// No XCD remap (R6/R7), no reg-prefetch (R4), no cross-CTA pairing (R16).
__global__ __launch_bounds__(512) void flash_attn(const unsigned short* __restrict__ Qb,
                                                  const unsigned short* __restrict__ Kb,
                                                  const unsigned short* __restrict__ VTb,
                                                  unsigned short* __restrict__ Ob) {
  __shared__ unsigned short Ks[2][64 * 128];
  __shared__ unsigned short Vs[2][128 * 64];
  __shared__ unsigned short Ps[8 * 16 * 64];   // stride 64, XOR-swizzled
  const int b = blockIdx.z, h = blockIdx.y;
  const int jj = blockIdx.x;            // 0..7
  const int tid = threadIdx.x;
  const int w = tid >> 6, l = tid & 63;
  const int lg = l >> 4, lr = l & 15;
  const float scale2 = 0.12751743f;     // (1/sqrt(128)) * log2(e)

  const unsigned short* Kbase = Kb + (size_t)b * 2048 * 2048 + h * 128;
  const unsigned short* Vbase = VTb + (size_t)(b * 16 + h) * 128 * 2048;

  // stage K/V tile kv0 into buffer bi (linear LDS dest, pre-swizzled source)
  auto stage = [&](int bi, int kv0) {
#pragma unroll
    for (int i = 0; i < 2; ++i) {
      int c = tid + 512 * i;
      int r = c >> 4, dbl = (c & 15) ^ (r & 7);
      GLOAD_LDS16(Kbase + (size_t)(kv0 + r) * 2048 + dbl * 8, &Ks[bi][c * 8]);
    }
#pragma unroll
    for (int i = 0; i < 2; ++i) {
      int c = tid + 512 * i;
      int d = c >> 3, kbl = (c & 7) ^ ((c >> 3) & 7);
      GLOAD_LDS16(Vbase + (size_t)d * 2048 + kv0 + kbl * 8, &Vs[bi][c * 8]);
    }
  };

  for (int pass = 0; pass < 2; ++pass) {
    const int qp = pass ? (15 - jj) : jj;
    const int qblk = 2 * qp + (w >> 2);           // this wave-group's q-block
    const int qw0 = qblk * 64 + (w & 3) * 16;     // wave's 16 q-rows

    v8bf qf[4];
    {
      const unsigned short* qp_ = Qb + (size_t)(b * 2048 + qw0 + lr) * 2048 + h * 128 + lg * 8;
#pragma unroll
      for (int ds = 0; ds < 4; ++ds) qf[ds] = *(const v8bf*)(qp_ + ds * 32);
    }
    v4f oacc[8];
#pragma unroll
    for (int i = 0; i < 8; ++i) oacc[i] = (v4f){0, 0, 0, 0};
    float mrow[4] = {0, 0, 0, 0};
    float lsum[4] = {0, 0, 0, 0};

    const int tmax0 = 2 * jj + 1;       // pass-0's last tile (L2-warm reorder)
    const int ntiles = 2 * qp + 2;
    int cur = 0;
    // prologue: stage this pass's first tile
    stage(0, (pass ? tmax0 : 0) * 64);
    __syncthreads();

    for (int ti = 0; ti < ntiles; ++ti) {
      // prefetch next tile into the other buffer; lands during compute.
      if (ti + 1 < ntiles) {
        int kvtn = (pass && (ti + 1) <= tmax0) ? (tmax0 - (ti + 1)) : (ti + 1);
        stage(cur ^ 1, kvtn * 64);
      }
      const int kvt = (pass && ti <= tmax0) ? (tmax0 - ti) : ti;
      const int kv0 = kvt * 64;
      const char* Kbuf = (const char*)Ks[cur];
      const char* Vbuf = (const char*)Vs[cur];
      if (kv0 <= qw0 + 15) {            // wave-uniform causal skip
        float st[4][4];
        __builtin_amdgcn_s_setprio(1);
#pragma unroll
        for (int kt = 0; kt < 4; ++kt) {
          v4f sacc = (v4f){0, 0, 0, 0};
          int krow = kt * 16 + lr;
#pragma unroll
          for (int ds = 0; ds < 4; ++ds) {
            int off = (krow * 256 + ds * 64 + lg * 16) ^ ((krow & 7) << 4);
            v8bf kfr = *(const v8bf*)(Kbuf + off);
            sacc = __builtin_amdgcn_mfma_f32_16x16x32_bf16(qf[ds], kfr, sacc, 0, 0, 0);
          }
          int colk = kv0 + kt * 16 + lr;
#pragma unroll
          for (int r = 0; r < 4; ++r) {
            int qrow = qw0 + lg * 4 + r;
            st[kt][r] = (colk <= qrow) ? sacc[r] * scale2 : -1e30f;
          }
        }
        __builtin_amdgcn_s_setprio(0);
        if (ti == 0) {
          // fixed per-row reference from the first processed tile (always
          // fully unmasked for this wave's rows).
#pragma unroll
          for (int r = 0; r < 4; ++r) {
            float mx = fmaxf(fmaxf(st[0][r], st[1][r]), fmaxf(st[2][r], st[3][r]));
#pragma unroll
            for (int o = 1; o < 16; o <<= 1) mx = fmaxf(mx, __shfl_xor(mx, o));
            mrow[r] = mx;
          }
        }
#pragma unroll
        for (int r = 0; r < 4; ++r) {
          float ps = 0.f;
          const int prow = lg * 4 + r;
#pragma unroll
          for (int kt = 0; kt < 4; ++kt) {
            float p = exp2_raw(st[kt][r] - mrow[r]);
            ps += p;
            int poff = (prow * 128 + (kt * 16 + lr) * 2) ^ ((prow & 7) << 4);
            *(unsigned short*)((char*)Ps + w * 2048 + poff) =
                (unsigned short)(__float_as_uint(p) >> 16);   // trunc bf16
          }
          lsum[r] += ps;                 // per-lane partial (reduced in epilogue)
        }
        __builtin_amdgcn_s_setprio(1);
#pragma unroll
        for (int kh = 0; kh < 2; ++kh) {
          int poff = (lr * 128 + kh * 64 + lg * 16) ^ ((lr & 7) << 4);
          v8bf pa = *(const v8bf*)((const char*)Ps + w * 2048 + poff);
#pragma unroll
          for (int dt = 0; dt < 8; ++dt) {
            int d = dt * 16 + lr;
            int off = (d * 128 + kh * 64 + lg * 16) ^ ((d & 7) << 4);
            v8bf vfr = *(const v8bf*)(Vbuf + off);
            oacc[dt] = __builtin_amdgcn_mfma_f32_16x16x32_bf16(pa, vfr, oacc[dt], 0, 0, 0);
          }
        }
        __builtin_amdgcn_s_setprio(0);
      }
      __syncthreads();   // drains next tile's loads; protects buf reuse
      cur ^= 1;
    }
#pragma unroll
    for (int r = 0; r < 4; ++r) {
      float ls = lsum[r];
#pragma unroll
      for (int o = 1; o < 16; o <<= 1) ls += __shfl_xor(ls, o);
      float inv = 1.f / ls;
      size_t orow = (size_t)(b * 2048 + qw0 + lg * 4 + r) * 2048 + h * 128;
#pragma unroll
      for (int dt = 0; dt < 8; ++dt)
        Ob[orow + dt * 16 + lr] = b16(oacc[dt][r] * inv);
    }
  }
}

extern "C" void kernel_launch(void* const* d_in, const int* in_sizes, int n_in,
                              void* d_out, int out_size, void* d_ws, size_t ws_size,
                              hipStream_t stream) {
  const float* x    = (const float*)d_in[0];
  const float* Wdq  = (const float*)d_in[1];
  const float* Wuq  = (const float*)d_in[2];
  const float* Wdkv = (const float*)d_in[3];
  const float* Wuk  = (const float*)d_in[4];
  const float* Wuv  = (const float*)d_in[5];
  const float* Wqr  = (const float*)d_in[6];
  const float* Wkr  = (const float*)d_in[7];
  const float* gq   = (const float*)d_in[8];
  const float* gkv  = (const float*)d_in[9];
  const float* Wout = (const float*)d_in[10];
  const float* bout = (const float*)d_in[11];
  float* out = (float*)d_out;

  // ---- workspace layout (bf16 elems), ~69MB total ----
  const size_t M1 = 1024 * 1024;
  unsigned short* xb  = (unsigned short*)d_ws;   // [0,8M)   xb; later Qb
  unsigned short* Qb  = xb;
  unsigned short* T   = xb + 8 * M1;             // [8M,20M) T1 (bf16); later Ob
  unsigned short* Ob  = T;
  unsigned short* W1T = xb + 20 * M1;            // 4M   [2048][2048]
  unsigned short* W2T = xb + 24 * M1;            // 1M   [2048][512]
  unsigned short* W3T = xb + 25 * M1;            // 1.5M [3072][512]
  unsigned short* WoT = W3T + 1536 * 1024;       // 4M   [2048][2048]
  unsigned short* cq  = xb + 30 * M1 + 512 * 1024; // 2M
  unsigned short* ckv = cq + 2 * M1;             // 2M   (ends at 34.5M elems = 69MB)
  // ---- K and V^T live in d_out (32MB of its 33.5MB), dead before GEMM4 overwrites ----
  unsigned short* Kb = (unsigned short*)d_out;   // 8M elems [b][s][h*128+d]
  unsigned short* VT = Kb + 8 * M1;              // 8M elems [bh][d][s]

  dim3 b256(256);

  // prep: conv + all 9 weight transposes in one launch
  prep<<<dim3(18944), b256, 0, stream>>>(x, xb, Wdq, Wdkv, Wkr, Wuq, Wqr, Wuk, Wuv, Wout,
                                         W1T, W2T, W3T, WoT);

  // GEMM1: x @ [W_dq | W_dkv | W_kr] -> T1 (bf16)
  gemm_bt<1><<<dim3(16, 32), b256, 0, stream>>>(xb, W1T, T, nullptr, 4096, 2048, 2048);
  rmsnorm_rope<<<4096, b256, 0, stream>>>(T, gq, gkv, cq, ckv, Kb);
  // merged GEMM2+GEMM3: cq@W2T -> Qb (RoPE'd), ckv@W3T -> Kb + VT (transposed)
  gemm23<<<dim3(1280), b256, 0, stream>>>(cq, ckv, W2T, W3T, Qb, Kb, VT);

  flash_attn<<<dim3(8, 16, 2), dim3(512), 0, stream>>>(Qb, Kb, VT, Ob);  // T1 dead: Ob aliases T

  // GEMM4: O @ W_out + b_out -> out (fp32); Kb/VT in d_out are dead now
  gemm_bt<0><<<dim3(16, 32), b256, 0, stream>>>(Ob, WoT, out, bout, 4096, 2048, 2048);
}

// Round 19
// 246.562 us; speedup vs baseline: 1.0103x; 1.0103x over previous
//
#include <hip/hip_runtime.h>
#include <hip/hip_bf16.h>
#include <cstdint>

typedef __bf16 v8bf __attribute__((ext_vector_type(8)));
typedef float  v4f  __attribute__((ext_vector_type(4)));

__device__ __forceinline__ unsigned short b16(float f) {
  union { float f; unsigned u; } v; v.f = f;
  unsigned u = v.u;
  return (unsigned short)((u + 0x7fffu + ((u >> 16) & 1u)) >> 16);
}
__device__ __forceinline__ float bf2f(unsigned short u) {
  union { unsigned u; float f; } v; v.u = ((unsigned)u) << 16; return v.f;
}
// raw 2^x — v_exp_f32 IS exp2; bypasses libm exp2f's precise path (R11 lesson)
__device__ __forceinline__ float exp2_raw(float x) {
  float r;
  asm("v_exp_f32 %0, %1" : "=v"(r) : "v"(x));
  return r;
}

#define GLOAD_LDS16(g, l)                                                     \
  __builtin_amdgcn_global_load_lds(                                           \
      (const __attribute__((address_space(1))) void*)(g),                     \
      (__attribute__((address_space(3))) void*)(l), 16, 0, 0)

// ---------------- prep: x fp32->bf16 convert + all 9 weight transposes, ONE launch --------
__global__ __launch_bounds__(256) void prep(const float* __restrict__ x,
                                            unsigned short* __restrict__ xb,
                                            const float* __restrict__ Wdq,
                                            const float* __restrict__ Wdkv,
                                            const float* __restrict__ Wkr,
                                            const float* __restrict__ Wuq,
                                            const float* __restrict__ Wqr,
                                            const float* __restrict__ Wuk,
                                            const float* __restrict__ Wuv,
                                            const float* __restrict__ Wout,
                                            unsigned short* __restrict__ W1T,
                                            unsigned short* __restrict__ W2T,
                                            unsigned short* __restrict__ W3T,
                                            unsigned short* __restrict__ WoT) {
  const int tid = threadIdx.x;
  int bid = blockIdx.x;
  if (bid < 8192) {
    size_t idx = (size_t)bid * 256 + tid;
    v4f v = *(const v4f*)(x + idx * 4);
    unsigned long long p = (unsigned long long)b16(v[0]) |
                           ((unsigned long long)b16(v[1]) << 16) |
                           ((unsigned long long)b16(v[2]) << 32) |
                           ((unsigned long long)b16(v[3]) << 48);
    *(unsigned long long*)(xb + idx * 4) = p;
    return;
  }
  __shared__ float tile[32][33];
  bid -= 8192;
  const float* in; unsigned short* out; int C, R, gx;
  if (bid < 1024)      { in = Wdq;  out = W1T;                        C = 512;  R = 2048; gx = 16; }
  else if (bid < 2048) { in = Wdkv; out = W1T + (size_t)512 * 2048;   C = 512;  R = 2048; gx = 16; bid -= 1024; }
  else if (bid < 4096) { in = Wkr;  out = W1T + (size_t)1024 * 2048;  C = 1024; R = 2048; gx = 32; bid -= 2048; }
  else if (bid < 4608) { in = Wuq;  out = W2T;                        C = 1024; R = 512;  gx = 32; bid -= 4096; }
  else if (bid < 5120) { in = Wqr;  out = W2T + (size_t)1024 * 512;   C = 1024; R = 512;  gx = 32; bid -= 4608; }
  else if (bid < 5632) { in = Wuk;  out = W3T;                        C = 1024; R = 512;  gx = 32; bid -= 5120; }
  else if (bid < 6656) { in = Wuv;  out = W3T + (size_t)1024 * 512;   C = 2048; R = 512;  gx = 64; bid -= 5632; }
  else                 { in = Wout; out = WoT;                        C = 2048; R = 2048; gx = 64; bid -= 6656; }
  const int c0 = (bid % gx) * 32, r0 = (bid / gx) * 32;
  const int xx = tid & 31, yy = tid >> 5;
#pragma unroll
  for (int i = 0; i < 4; ++i)
    tile[yy + 8 * i][xx] = in[(size_t)(r0 + yy + 8 * i) * C + c0 + xx];
  __syncthreads();
#pragma unroll
  for (int i = 0; i < 4; ++i)
    out[(size_t)(c0 + yy + 8 * i) * R + r0 + xx] = b16(tile[xx][yy + 8 * i]);
}

// ---------------- GEMM: C[M,N] = A[M,K](bf16) * BT[N,K](bf16) ----------------
// m97 recipe: 128x128 tile, BK=32, 4 waves (2x2), global_load_lds width=16,
// LINEAR [128][32] LDS. Bijective XCD swizzle (nwg % 8 == 0).
// MODE 0: fp32 + bias -> C0.  MODE 1: bf16 -> C0 (stride N).
template <int MODE>
__global__ __launch_bounds__(256) void gemm_bt(const unsigned short* __restrict__ A,
                                               const unsigned short* __restrict__ BT,
                                               void* __restrict__ C0,
                                               const float* __restrict__ bias,
                                               int M, int N, int K) {
  __shared__ unsigned short As[128 * 32];
  __shared__ unsigned short Bs[128 * 32];
  const int tid = threadIdx.x;
  const int w = tid >> 6, l = tid & 63;
  const int wm = w >> 1, wn = w & 1;
  const int lg = l >> 4, lr = l & 15;
  const int nwg = gridDim.x * gridDim.y;
  const int f = blockIdx.y * gridDim.x + blockIdx.x;
  const int swz = (f & 7) * (nwg >> 3) + (f >> 3);
  const int m0 = (swz / gridDim.x) * 128, n0 = (swz % gridDim.x) * 128;

  const int srow = tid >> 2, scol = (tid & 3) * 8;
  const unsigned short* Ap0 = A  + (size_t)(m0 + srow) * K + scol;
  const unsigned short* Ap1 = A  + (size_t)(m0 + 64 + srow) * K + scol;
  const unsigned short* Bp0 = BT + (size_t)(n0 + srow) * K + scol;
  const unsigned short* Bp1 = BT + (size_t)(n0 + 64 + srow) * K + scol;
  unsigned short* Ad0 = As + tid * 8;
  unsigned short* Ad1 = As + 2048 + tid * 8;
  unsigned short* Bd0 = Bs + tid * 8;
  unsigned short* Bd1 = Bs + 2048 + tid * 8;

  v4f acc[4][4];
#pragma unroll
  for (int i = 0; i < 4; ++i)
#pragma unroll
    for (int j = 0; j < 4; ++j) acc[i][j] = (v4f){0.f, 0.f, 0.f, 0.f};

  for (int k0 = 0; k0 < K; k0 += 32) {
    GLOAD_LDS16(Ap0 + k0, Ad0);
    GLOAD_LDS16(Ap1 + k0, Ad1);
    GLOAD_LDS16(Bp0 + k0, Bd0);
    GLOAD_LDS16(Bp1 + k0, Bd1);
    __syncthreads();
    v8bf af[4], bfr[4];
#pragma unroll
    for (int mi = 0; mi < 4; ++mi)
      af[mi] = *(const v8bf*)&As[(wm * 64 + mi * 16 + lr) * 32 + lg * 8];
#pragma unroll
    for (int ni = 0; ni < 4; ++ni)
      bfr[ni] = *(const v8bf*)&Bs[(wn * 64 + ni * 16 + lr) * 32 + lg * 8];
#pragma unroll
    for (int mi = 0; mi < 4; ++mi)
#pragma unroll
      for (int ni = 0; ni < 4; ++ni)
        acc[mi][ni] = __builtin_amdgcn_mfma_f32_16x16x32_bf16(af[mi], bfr[ni], acc[mi][ni], 0, 0, 0);
    __syncthreads();
  }
#pragma unroll
  for (int mi = 0; mi < 4; ++mi)
#pragma unroll
    for (int ni = 0; ni < 4; ++ni) {
      const int col = n0 + wn * 64 + ni * 16 + lr;
#pragma unroll
      for (int rr = 0; rr < 4; ++rr) {
        const int row = m0 + wm * 64 + mi * 16 + lg * 4 + rr;
        const float v = acc[mi][ni][rr];
        if (MODE == 0) {
          ((float*)C0)[(size_t)row * N + col] = v + bias[col];
        } else {
          ((unsigned short*)C0)[(size_t)row * N + col] = b16(v);
        }
      }
    }
}

// ---------------- merged GEMM2+GEMM3 (both K=512, independent) ----------------
__global__ __launch_bounds__(256) void gemm23(const unsigned short* __restrict__ cq,
                                              const unsigned short* __restrict__ ckv,
                                              const unsigned short* __restrict__ W2T,
                                              const unsigned short* __restrict__ W3T,
                                              unsigned short* __restrict__ Qb,
                                              unsigned short* __restrict__ Kb,
                                              unsigned short* __restrict__ VT) {
  __shared__ unsigned short As[128 * 32];
  __shared__ unsigned short Bs[128 * 32];
  const int tid = threadIdx.x;
  const int w = tid >> 6, l = tid & 63;
  const int wm = w >> 1, wn = w & 1;
  const int lg = l >> 4, lr = l & 15;
  const int f = blockIdx.x;                      // 0..1279
  const int swz = (f & 7) * 160 + (f >> 3);      // bijective XCD swizzle (1280/8=160)
  const bool is3 = swz >= 512;
  const int t = is3 ? swz - 512 : swz;
  const int gx = is3 ? 24 : 16;
  const int m0 = (t / gx) * 128, n0 = (t % gx) * 128;
  const unsigned short* A  = is3 ? ckv : cq;
  const unsigned short* BT = is3 ? W3T : W2T;
  const int K = 512;

  const int srow = tid >> 2, scol = (tid & 3) * 8;
  const unsigned short* Ap0 = A  + (size_t)(m0 + srow) * K + scol;
  const unsigned short* Ap1 = A  + (size_t)(m0 + 64 + srow) * K + scol;
  const unsigned short* Bp0 = BT + (size_t)(n0 + srow) * K + scol;
  const unsigned short* Bp1 = BT + (size_t)(n0 + 64 + srow) * K + scol;
  unsigned short* Ad0 = As + tid * 8;
  unsigned short* Ad1 = As + 2048 + tid * 8;
  unsigned short* Bd0 = Bs + tid * 8;
  unsigned short* Bd1 = Bs + 2048 + tid * 8;

  v4f acc[4][4];
#pragma unroll
  for (int i = 0; i < 4; ++i)
#pragma unroll
    for (int j = 0; j < 4; ++j) acc[i][j] = (v4f){0.f, 0.f, 0.f, 0.f};

  for (int k0 = 0; k0 < K; k0 += 32) {
    GLOAD_LDS16(Ap0 + k0, Ad0);
    GLOAD_LDS16(Ap1 + k0, Ad1);
    GLOAD_LDS16(Bp0 + k0, Bd0);
    GLOAD_LDS16(Bp1 + k0, Bd1);
    __syncthreads();
    v8bf af[4], bfr[4];
#pragma unroll
    for (int mi = 0; mi < 4; ++mi)
      af[mi] = *(const v8bf*)&As[(wm * 64 + mi * 16 + lr) * 32 + lg * 8];
#pragma unroll
    for (int ni = 0; ni < 4; ++ni)
      bfr[ni] = *(const v8bf*)&Bs[(wn * 64 + ni * 16 + lr) * 32 + lg * 8];
#pragma unroll
    for (int mi = 0; mi < 4; ++mi)
#pragma unroll
      for (int ni = 0; ni < 4; ++ni)
        acc[mi][ni] = __builtin_amdgcn_mfma_f32_16x16x32_bf16(af[mi], bfr[ni], acc[mi][ni], 0, 0, 0);
    __syncthreads();
  }

#pragma unroll
  for (int mi = 0; mi < 4; ++mi)
#pragma unroll
    for (int ni = 0; ni < 4; ++ni) {
      const int col = n0 + wn * 64 + ni * 16 + lr;
      const int row0 = m0 + wm * 64 + mi * 16 + lg * 4;
      if (!is3) {
        if (col < 1024) {
          int qc = (col >> 6) * 128 + (col & 63);
#pragma unroll
          for (int rr = 0; rr < 4; ++rr)
            Qb[(size_t)(row0 + rr) * 2048 + qc] = b16(acc[mi][ni][rr]);
        } else {
          int cc = col - 1024, d = cc & 63;
          int qc = (cc >> 6) * 128 + 64 + d;
#pragma unroll
          for (int rr = 0; rr < 4; ++rr) {
            int s = (row0 + rr) & 2047;
            float ang = (float)s * __expf(-(float)(d & 31) * 0.14391156831f);
            float sn, cs; __sincosf(ang, &sn, &cs);
            Qb[(size_t)(row0 + rr) * 2048 + qc] = b16(acc[mi][ni][rr] * (cs + sn));
          }
        }
      } else {
        if (col < 1024) {
          int kc = (col >> 6) * 128 + (col & 63);
#pragma unroll
          for (int rr = 0; rr < 4; ++rr)
            Kb[(size_t)(row0 + rr) * 2048 + kc] = b16(acc[mi][ni][rr]);
        } else {
          int hd = col - 1024, h = hd >> 7, d = hd & 127;
          int b = row0 >> 11, s = row0 & 2047;
          unsigned long long p =
              (unsigned long long)b16(acc[mi][ni][0]) |
              ((unsigned long long)b16(acc[mi][ni][1]) << 16) |
              ((unsigned long long)b16(acc[mi][ni][2]) << 32) |
              ((unsigned long long)b16(acc[mi][ni][3]) << 48);
          *(unsigned long long*)&VT[(size_t)((b * 16 + h) * 128 + d) * 2048 + s] = p;
        }
      }
    }
}

// ---------------- RMSNorm + RoPE k_rot ----------------
__global__ __launch_bounds__(256) void rmsnorm_rope(const unsigned short* __restrict__ T1,
                                                    const float* __restrict__ gq,
                                                    const float* __restrict__ gkv,
                                                    unsigned short* __restrict__ cq,
                                                    unsigned short* __restrict__ ckv,
                                                    unsigned short* __restrict__ Kb) {
  const int row = blockIdx.x;
  const int t = threadIdx.x;
  const int s = row & 2047;
  const unsigned short* rp = T1 + (size_t)row * 2048;
  float xq0 = bf2f(rp[t]), xq1 = bf2f(rp[256 + t]);
  float xk0 = bf2f(rp[512 + t]), xk1 = bf2f(rp[768 + t]);
  float sq = xq0 * xq0 + xq1 * xq1;
  float sk = xk0 * xk0 + xk1 * xk1;
#pragma unroll
  for (int o = 1; o < 64; o <<= 1) { sq += __shfl_xor(sq, o); sk += __shfl_xor(sk, o); }
  __shared__ float red[8];
  if ((t & 63) == 0) { red[t >> 6] = sq; red[4 + (t >> 6)] = sk; }
  __syncthreads();
  float rq = rsqrtf((red[0] + red[1] + red[2] + red[3]) * (1.f / 512.f) + 1e-5f);
  float rk = rsqrtf((red[4] + red[5] + red[6] + red[7]) * (1.f / 512.f) + 1e-5f);
  cq[(size_t)row * 512 + t]        = b16(gq[t] * xq0 * rq);
  cq[(size_t)row * 512 + 256 + t]  = b16(gq[256 + t] * xq1 * rq);
  ckv[(size_t)row * 512 + t]       = b16(gkv[t] * xk0 * rk);
  ckv[(size_t)row * 512 + 256 + t] = b16(gkv[256 + t] * xk1 * rk);
#pragma unroll
  for (int i = 0; i < 4; ++i) {
    int j = t + 256 * i;                 // 0..1023
    int hh = j >> 6, d = j & 63;
    float ang = (float)s * __expf(-(float)(d & 31) * 0.14391156831f); // ln(10000)/64
    float sn, cs; __sincosf(ang, &sn, &cs);
    Kb[(size_t)row * 2048 + hh * 128 + 64 + d] = b16(bf2f(rp[1024 + j]) * (cs + sn));
  }
}

// ---------------- causal flash attention (FINAL: R17 config, best measured) ----------------
// 8-wave KV-shared CTA (2 adjacent q-blocks share every staged K/V tile),
// within-CTA complementary pairing (jj then 15-jj: exactly 34 tiles/CTA),
// 256 CTAs = 1/CU, K/V LDS double-buffer covering the per-tile stage chain
// (dbuf pays ONLY at 1 CTA/CU — R14 null at 2/CU, R17 -5us at 1/CU).
// Fixed-reference exp2 softmax (R13), raw v_exp_f32 (R11), T5 setprio,
// gload_lds staging w/ pre-swizzled source, Ps stride-72 padding.
// Structural floor of this family: ~34 sequential tile-passes; no pipe >30%.
// Dead ends (measured): XCD remap (R6/R7 +54us), reg-prefetch (R4 occupancy),
// cross-CTA pairing (R16 +34us), Ps-swz for 2/CU (R18: grid=256 caps at 1/CU),
// libm exp2f (R11 +12us), 8-wave lockstep QBLK=128 (R3 +36us).
__global__ __launch_bounds__(512) void flash_attn(const unsigned short* __restrict__ Qb,
                                                  const unsigned short* __restrict__ Kb,
                                                  const unsigned short* __restrict__ VTb,
                                                  unsigned short* __restrict__ Ob) {
  __shared__ unsigned short Ks[2][64 * 128];
  __shared__ unsigned short Vs[2][128 * 64];
  __shared__ unsigned short Ps[8 * 16 * 72];
  const int b = blockIdx.z, h = blockIdx.y;
  const int jj = blockIdx.x;            // 0..7
  const int tid = threadIdx.x;
  const int w = tid >> 6, l = tid & 63;
  const int lg = l >> 4, lr = l & 15;
  const float scale2 = 0.12751743f;     // (1/sqrt(128)) * log2(e)

  const unsigned short* Kbase = Kb + (size_t)b * 2048 * 2048 + h * 128;
  const unsigned short* Vbase = VTb + (size_t)(b * 16 + h) * 128 * 2048;

  // stage K/V tile kv0 into buffer bi (linear LDS dest, pre-swizzled source)
  auto stage = [&](int bi, int kv0) {
#pragma unroll
    for (int i = 0; i < 2; ++i) {
      int c = tid + 512 * i;
      int r = c >> 4, dbl = (c & 15) ^ (r & 7);
      GLOAD_LDS16(Kbase + (size_t)(kv0 + r) * 2048 + dbl * 8, &Ks[bi][c * 8]);
    }
#pragma unroll
    for (int i = 0; i < 2; ++i) {
      int c = tid + 512 * i;
      int d = c >> 3, kbl = (c & 7) ^ ((c >> 3) & 7);
      GLOAD_LDS16(Vbase + (size_t)d * 2048 + kv0 + kbl * 8, &Vs[bi][c * 8]);
    }
  };

  for (int pass = 0; pass < 2; ++pass) {
    const int qp = pass ? (15 - jj) : jj;
    const int qblk = 2 * qp + (w >> 2);           // this wave-group's q-block
    const int qw0 = qblk * 64 + (w & 3) * 16;     // wave's 16 q-rows

    v8bf qf[4];
    {
      const unsigned short* qp_ = Qb + (size_t)(b * 2048 + qw0 + lr) * 2048 + h * 128 + lg * 8;
#pragma unroll
      for (int ds = 0; ds < 4; ++ds) qf[ds] = *(const v8bf*)(qp_ + ds * 32);
    }
    v4f oacc[8];
#pragma unroll
    for (int i = 0; i < 8; ++i) oacc[i] = (v4f){0, 0, 0, 0};
    float mrow[4] = {0, 0, 0, 0};
    float lsum[4] = {0, 0, 0, 0};

    const int tmax0 = 2 * jj + 1;       // pass-0's last tile (L2-warm reorder)
    const int ntiles = 2 * qp + 2;
    int cur = 0;
    // prologue: stage this pass's first tile
    stage(0, (pass ? tmax0 : 0) * 64);
    __syncthreads();

    for (int ti = 0; ti < ntiles; ++ti) {
      // prefetch next tile into the other buffer; lands during compute.
      if (ti + 1 < ntiles) {
        int kvtn = (pass && (ti + 1) <= tmax0) ? (tmax0 - (ti + 1)) : (ti + 1);
        stage(cur ^ 1, kvtn * 64);
      }
      const int kvt = (pass && ti <= tmax0) ? (tmax0 - ti) : ti;
      const int kv0 = kvt * 64;
      const char* Kbuf = (const char*)Ks[cur];
      const char* Vbuf = (const char*)Vs[cur];
      if (kv0 <= qw0 + 15) {            // wave-uniform causal skip
        float st[4][4];
        __builtin_amdgcn_s_setprio(1);
#pragma unroll
        for (int kt = 0; kt < 4; ++kt) {
          v4f sacc = (v4f){0, 0, 0, 0};
          int krow = kt * 16 + lr;
#pragma unroll
          for (int ds = 0; ds < 4; ++ds) {
            int off = (krow * 256 + ds * 64 + lg * 16) ^ ((krow & 7) << 4);
            v8bf kfr = *(const v8bf*)(Kbuf + off);
            sacc = __builtin_amdgcn_mfma_f32_16x16x32_bf16(qf[ds], kfr, sacc, 0, 0, 0);
          }
          int colk = kv0 + kt * 16 + lr;
#pragma unroll
          for (int r = 0; r < 4; ++r) {
            int qrow = qw0 + lg * 4 + r;
            st[kt][r] = (colk <= qrow) ? sacc[r] * scale2 : -1e30f;
          }
        }
        __builtin_amdgcn_s_setprio(0);
        if (ti == 0) {
          // fixed per-row reference from the first processed tile (always
          // fully unmasked for this wave's rows: pass0 kvt=0; pass1
          // kvt=tmax0=2jj+1 <= qblk=2(15-jj)+g for jj<=7).
#pragma unroll
          for (int r = 0; r < 4; ++r) {
            float mx = fmaxf(fmaxf(st[0][r], st[1][r]), fmaxf(st[2][r], st[3][r]));
#pragma unroll
            for (int o = 1; o < 16; o <<= 1) mx = fmaxf(mx, __shfl_xor(mx, o));
            mrow[r] = mx;
          }
        }
#pragma unroll
        for (int r = 0; r < 4; ++r) {
          float ps = 0.f;
#pragma unroll
          for (int kt = 0; kt < 4; ++kt) {
            float p = exp2_raw(st[kt][r] - mrow[r]);
            ps += p;
            Ps[w * 1152 + (lg * 4 + r) * 72 + kt * 16 + lr] =
                (unsigned short)(__float_as_uint(p) >> 16);   // trunc bf16
          }
          lsum[r] += ps;                 // per-lane partial (reduced in epilogue)
        }
        __builtin_amdgcn_s_setprio(1);
#pragma unroll
        for (int kh = 0; kh < 2; ++kh) {
          v8bf pa = *(const v8bf*)((const char*)Ps + w * 2304 + lr * 144 + kh * 64 + lg * 16);
#pragma unroll
          for (int dt = 0; dt < 8; ++dt) {
            int d = dt * 16 + lr;
            int off = (d * 128 + kh * 64 + lg * 16) ^ ((d & 7) << 4);
            v8bf vfr = *(const v8bf*)(Vbuf + off);
            oacc[dt] = __builtin_amdgcn_mfma_f32_16x16x32_bf16(pa, vfr, oacc[dt], 0, 0, 0);
          }
        }
        __builtin_amdgcn_s_setprio(0);
      }
      __syncthreads();   // drains next tile's loads; protects buf reuse
      cur ^= 1;
    }
#pragma unroll
    for (int r = 0; r < 4; ++r) {
      float ls = lsum[r];
#pragma unroll
      for (int o = 1; o < 16; o <<= 1) ls += __shfl_xor(ls, o);
      float inv = 1.f / ls;
      size_t orow = (size_t)(b * 2048 + qw0 + lg * 4 + r) * 2048 + h * 128;
#pragma unroll
      for (int dt = 0; dt < 8; ++dt)
        Ob[orow + dt * 16 + lr] = b16(oacc[dt][r] * inv);
    }
  }
}

extern "C" void kernel_launch(void* const* d_in, const int* in_sizes, int n_in,
                              void* d_out, int out_size, void* d_ws, size_t ws_size,
                              hipStream_t stream) {
  const float* x    = (const float*)d_in[0];
  const float* Wdq  = (const float*)d_in[1];
  const float* Wuq  = (const float*)d_in[2];
  const float* Wdkv = (const float*)d_in[3];
  const float* Wuk  = (const float*)d_in[4];
  const float* Wuv  = (const float*)d_in[5];
  const float* Wqr  = (const float*)d_in[6];
  const float* Wkr  = (const float*)d_in[7];
  const float* gq   = (const float*)d_in[8];
  const float* gkv  = (const float*)d_in[9];
  const float* Wout = (const float*)d_in[10];
  const float* bout = (const float*)d_in[11];
  float* out = (float*)d_out;

  // ---- workspace layout (bf16 elems), ~69MB total ----
  const size_t M1 = 1024 * 1024;
  unsigned short* xb  = (unsigned short*)d_ws;   // [0,8M)   xb; later Qb
  unsigned short* Qb  = xb;
  unsigned short* T   = xb + 8 * M1;             // [8M,20M) T1 (bf16); later Ob
  unsigned short* Ob  = T;
  unsigned short* W1T = xb + 20 * M1;            // 4M   [2048][2048]
  unsigned short* W2T = xb + 24 * M1;            // 1M   [2048][512]
  unsigned short* W3T = xb + 25 * M1;            // 1.5M [3072][512]
  unsigned short* WoT = W3T + 1536 * 1024;       // 4M   [2048][2048]
  unsigned short* cq  = xb + 30 * M1 + 512 * 1024; // 2M
  unsigned short* ckv = cq + 2 * M1;             // 2M   (ends at 34.5M elems = 69MB)
  // ---- K and V^T live in d_out (32MB of its 33.5MB), dead before GEMM4 overwrites ----
  unsigned short* Kb = (unsigned short*)d_out;   // 8M elems [b][s][h*128+d]
  unsigned short* VT = Kb + 8 * M1;              // 8M elems [bh][d][s]

  dim3 b256(256);

  // prep: conv + all 9 weight transposes in one launch
  prep<<<dim3(18944), b256, 0, stream>>>(x, xb, Wdq, Wdkv, Wkr, Wuq, Wqr, Wuk, Wuv, Wout,
                                         W1T, W2T, W3T, WoT);

  // GEMM1: x @ [W_dq | W_dkv | W_kr] -> T1 (bf16)
  gemm_bt<1><<<dim3(16, 32), b256, 0, stream>>>(xb, W1T, T, nullptr, 4096, 2048, 2048);
  rmsnorm_rope<<<4096, b256, 0, stream>>>(T, gq, gkv, cq, ckv, Kb);
  // merged GEMM2+GEMM3: cq@W2T -> Qb (RoPE'd), ckv@W3T -> Kb + VT (transposed)
  gemm23<<<dim3(1280), b256, 0, stream>>>(cq, ckv, W2T, W3T, Qb, Kb, VT);

  flash_attn<<<dim3(8, 16, 2), dim3(512), 0, stream>>>(Qb, Kb, VT, Ob);  // T1 dead: Ob aliases T

  // GEMM4: O @ W_out + b_out -> out (fp32); Kb/VT in d_out are dead now
  gemm_bt<0><<<dim3(16, 32), b256, 0, stream>>>(Ob, WoT, out, bout, 4096, 2048, 2048);
}